// Round 1
// baseline (529.710 us; speedup 1.0000x reference)
//
#include <hip/hip_runtime.h>
#include <hip/hip_bf16.h>
#include <math.h>

#define N_NODES 20000
#define N_EDGES 320000
#define N_GRAPHS 64
#define OBS 64
#define EDGE_DIM 16
#define HEADS 4
#define HID 64
#define HC 256            // HEADS*HID
#define NEG_SLOPE 0.2f
#define EPSF 1e-16f

// ---------------------------------------------------------------- utilities
__global__ __launch_bounds__(256) void zero_kernel(unsigned int* __restrict__ p, int n) {
    int i = blockIdx.x * 256 + threadIdx.x;
    if (i < n) p[i] = 0u;
}

// ---------------------------------------------------------------- CSR build
__global__ __launch_bounds__(256) void count_kernel(const int* __restrict__ ei, int* __restrict__ counts) {
    int e = blockIdx.x * 256 + threadIdx.x;
    if (e >= N_EDGES) return;
    atomicAdd(&counts[ei[N_EDGES + e]], 1);
}

__global__ __launch_bounds__(256) void scan_kernel(const int* __restrict__ counts,
                                                   int* __restrict__ row_start,
                                                   int* __restrict__ cursor, int n) {
    __shared__ int sd[256];
    __shared__ int carry_s;
    int t = threadIdx.x;
    if (t == 0) carry_s = 0;
    __syncthreads();
    for (int base = 0; base < n; base += 256) {
        int i = base + t;
        int v = (i < n) ? counts[i] : 0;
        sd[t] = v;
        __syncthreads();
        #pragma unroll
        for (int off = 1; off < 256; off <<= 1) {
            int add = (t >= off) ? sd[t - off] : 0;
            __syncthreads();
            sd[t] += add;
            __syncthreads();
        }
        int incl = sd[t];
        int carry = carry_s;
        int excl = incl - v;
        if (i < n) { row_start[i] = carry + excl; cursor[i] = carry + excl; }
        __syncthreads();
        if (t == 255) carry_s += incl;   // incl of t=255 == block total
        __syncthreads();
    }
}

__global__ __launch_bounds__(256) void fill_kernel(const int* __restrict__ ei,
                                                   int* __restrict__ cursor,
                                                   int* __restrict__ eid) {
    int e = blockIdx.x * 256 + threadIdx.x;
    if (e >= N_EDGES) return;
    int d = ei[N_EDGES + e];
    int pos = atomicAdd(&cursor[d], 1);
    eid[pos] = e;
}

// ---------------------------------------------------------------- w_eff[h][d] = sum_c We[d, h*64+c] * att_edge[h,c]
__global__ void weff_kernel(const float* __restrict__ We, const float* __restrict__ att_edge,
                            float* __restrict__ w_eff) {
    int t = threadIdx.x;          // 64 threads
    int hh = t >> 4, d = t & 15;
    float acc = 0.f;
    #pragma unroll 8
    for (int c = 0; c < HID; ++c)
        acc += We[d * HC + hh * HID + c] * att_edge[hh * HID + c];
    w_eff[hh * 16 + d] = acc;
}

// ---------------------------------------------------------------- GEMM: C[M,256] = X[M,K] @ W[K,256]
#define BM 64
#define BN 64
#define BK 16
__global__ __launch_bounds__(256) void gemm_kernel(const float* __restrict__ X,
                                                   const float* __restrict__ W,
                                                   float* __restrict__ C, int M, int K) {
    __shared__ float As[BK][68];   // padded: stride 68 floats (272B, 16B-aligned rows)
    __shared__ float Bs[BK][64];
    int t = threadIdx.x;
    int tx = t & 15, ty = t >> 4;
    int m0 = blockIdx.x * BM;
    int n0 = blockIdx.y * BN;
    float acc[4][4] = {};
    for (int k0 = 0; k0 < K; k0 += BK) {
        // stage A (transposed): thread -> row r=t>>2 (0..63), k-quad q=t&3
        {
            int r = t >> 2, q = t & 3;
            int m = m0 + r;
            float4 v = make_float4(0.f, 0.f, 0.f, 0.f);
            if (m < M) v = *(const float4*)(X + (size_t)m * K + k0 + q * 4);
            As[q * 4 + 0][r] = v.x;
            As[q * 4 + 1][r] = v.y;
            As[q * 4 + 2][r] = v.z;
            As[q * 4 + 3][r] = v.w;
        }
        // stage B: thread -> k-row kr=t>>4 (0..15), col-quad n4=(t&15)*4
        {
            int kr = t >> 4, n4 = (t & 15) * 4;
            float4 v = *(const float4*)(W + (size_t)(k0 + kr) * HC + n0 + n4);
            *(float4*)&Bs[kr][n4] = v;
        }
        __syncthreads();
        #pragma unroll
        for (int kk = 0; kk < BK; ++kk) {
            float4 a4 = *(const float4*)&As[kk][ty * 4];
            float4 b4 = *(const float4*)&Bs[kk][tx * 4];
            float av[4] = {a4.x, a4.y, a4.z, a4.w};
            float bv[4] = {b4.x, b4.y, b4.z, b4.w};
            #pragma unroll
            for (int i = 0; i < 4; ++i)
                #pragma unroll
                for (int j = 0; j < 4; ++j)
                    acc[i][j] += av[i] * bv[j];
        }
        __syncthreads();
    }
    #pragma unroll
    for (int i = 0; i < 4; ++i) {
        int m = m0 + ty * 4 + i;
        if (m < M)
            *(float4*)(C + (size_t)m * HC + n0 + tx * 4) =
                make_float4(acc[i][0], acc[i][1], acc[i][2], acc[i][3]);
    }
}

// ---------------------------------------------------------------- per-node attention dots
__global__ __launch_bounds__(256) void attdot_kernel(const float* __restrict__ h,
                                                     const float* __restrict__ att_src,
                                                     const float* __restrict__ att_dst,
                                                     float* __restrict__ a_src,
                                                     float* __restrict__ a_dst) {
    int wid = threadIdx.x >> 6, lane = threadIdx.x & 63;
    int n = blockIdx.x * 4 + wid;
    if (n >= N_NODES) return;
    const float* hr = h + (size_t)n * HC;
    float s[4], d[4];
    #pragma unroll
    for (int hh = 0; hh < 4; ++hh) {
        float v = hr[hh * 64 + lane];
        s[hh] = v * att_src[hh * 64 + lane];
        d[hh] = v * att_dst[hh * 64 + lane];
    }
    #pragma unroll
    for (int o = 32; o > 0; o >>= 1) {
        #pragma unroll
        for (int hh = 0; hh < 4; ++hh) {
            s[hh] += __shfl_xor(s[hh], o, 64);
            d[hh] += __shfl_xor(d[hh], o, 64);
        }
    }
    if (lane == 0) {
        *(float4*)(a_src + (size_t)n * 4) = make_float4(s[0], s[1], s[2], s[3]);
        *(float4*)(a_dst + (size_t)n * 4) = make_float4(d[0], d[1], d[2], d[3]);
    }
}

// ---------------------------------------------------------------- per-edge raw attention logits
__global__ __launch_bounds__(256) void alpha_kernel(const int* __restrict__ ei,
                                                    const float* __restrict__ edge_attr,
                                                    const float* __restrict__ w_eff,
                                                    const float* __restrict__ a_src,
                                                    const float* __restrict__ a_dst,
                                                    float4* __restrict__ alpha_out) {
    __shared__ float wsh[64];
    int t = threadIdx.x;
    if (t < 64) wsh[t] = w_eff[t];
    __syncthreads();
    int e = blockIdx.x * 256 + t;
    if (e >= N_EDGES) return;
    int s = ei[e], d = ei[N_EDGES + e];
    const float* ea = edge_attr + (size_t)e * EDGE_DIM;
    float x[16];
    #pragma unroll
    for (int i = 0; i < 16; i += 4) {
        float4 v = *(const float4*)(ea + i);
        x[i] = v.x; x[i + 1] = v.y; x[i + 2] = v.z; x[i + 3] = v.w;
    }
    float4 as = *(const float4*)(a_src + (size_t)s * 4);
    float4 ad = *(const float4*)(a_dst + (size_t)d * 4);
    float asv[4] = {as.x, as.y, as.z, as.w};
    float adv[4] = {ad.x, ad.y, ad.z, ad.w};
    float al[4];
    #pragma unroll
    for (int hh = 0; hh < 4; ++hh) {
        float acc = 0.f;
        #pragma unroll
        for (int i = 0; i < 16; ++i) acc += x[i] * wsh[hh * 16 + i];
        float v = asv[hh] + adv[hh] + acc;
        al[hh] = v > 0.f ? v : NEG_SLOPE * v;   // leaky_relu
    }
    alpha_out[e] = make_float4(al[0], al[1], al[2], al[3]);
}

// ---------------------------------------------------------------- aggregate: wave per node, online softmax + gather
__global__ __launch_bounds__(256) void aggregate_kernel(const int* __restrict__ ei,
                                                        const int* __restrict__ eid,
                                                        const int* __restrict__ row_start,
                                                        const int* __restrict__ counts,
                                                        const float4* __restrict__ alpha_raw,
                                                        const float* __restrict__ h,
                                                        const float* __restrict__ bias,
                                                        float* __restrict__ out) {
    int wid = threadIdx.x >> 6, lane = threadIdx.x & 63;
    int n = blockIdx.x * 4 + wid;
    if (n >= N_NODES) return;
    int start = row_start[n];
    int deg = counts[n];

    // pass A: per-head max over incoming edges (lane-parallel)
    float m0 = -INFINITY, m1 = -INFINITY, m2 = -INFINITY, m3 = -INFINITY;
    for (int i = lane; i < deg; i += 64) {
        float4 a = alpha_raw[eid[start + i]];
        m0 = fmaxf(m0, a.x); m1 = fmaxf(m1, a.y);
        m2 = fmaxf(m2, a.z); m3 = fmaxf(m3, a.w);
    }
    #pragma unroll
    for (int o = 32; o > 0; o >>= 1) {
        m0 = fmaxf(m0, __shfl_xor(m0, o, 64));
        m1 = fmaxf(m1, __shfl_xor(m1, o, 64));
        m2 = fmaxf(m2, __shfl_xor(m2, o, 64));
        m3 = fmaxf(m3, __shfl_xor(m3, o, 64));
    }

    // pass B: serial over edges, fused exp-sum + weighted gather of h[src]
    float acc0 = 0.f, acc1 = 0.f, acc2 = 0.f, acc3 = 0.f;
    float d0 = 0.f, d1 = 0.f, d2 = 0.f, d3 = 0.f;
    const int* ep = eid + start;
    for (int i = 0; i < deg; ++i) {
        int e = ep[i];
        int s = ei[e];
        float4 a = alpha_raw[e];
        float e0 = __expf(a.x - m0);
        float e1 = __expf(a.y - m1);
        float e2 = __expf(a.z - m2);
        float e3 = __expf(a.w - m3);
        d0 += e0; d1 += e1; d2 += e2; d3 += e3;
        const float* hr = h + (size_t)s * HC;
        acc0 += e0 * hr[lane];
        acc1 += e1 * hr[64 + lane];
        acc2 += e2 * hr[128 + lane];
        acc3 += e3 * hr[192 + lane];
    }
    float r0 = acc0 / (d0 + EPSF) + bias[lane];
    float r1 = acc1 / (d1 + EPSF) + bias[64 + lane];
    float r2 = acc2 / (d2 + EPSF) + bias[128 + lane];
    float r3 = acc3 / (d3 + EPSF) + bias[192 + lane];
    float* o = out + (size_t)n * HC;
    o[lane]       = fmaxf(r0, 0.f);
    o[64 + lane]  = fmaxf(r1, 0.f);
    o[128 + lane] = fmaxf(r2, 0.f);
    o[192 + lane] = fmaxf(r3, 0.f);
}

// ---------------------------------------------------------------- pooling (batch is sorted)
#define NPB 100
__global__ __launch_bounds__(256) void pool_kernel(const float* __restrict__ h,
                                                   const int* __restrict__ batch,
                                                   float* __restrict__ pooled,
                                                   int* __restrict__ gcounts) {
    int t = threadIdx.x;
    int n0 = blockIdx.x * NPB;
    int n1 = n0 + NPB;
    if (n1 > N_NODES) n1 = N_NODES;
    if (n0 >= N_NODES) return;
    int cur = batch[n0];
    float acc = 0.f;
    int cnt = 0;
    for (int n = n0; n < n1; ++n) {
        int g = batch[n];
        if (g != cur) {
            atomicAdd(&pooled[cur * HC + t], acc);
            if (t == 0) atomicAdd(&gcounts[cur], cnt);
            acc = 0.f; cnt = 0; cur = g;
        }
        acc += h[(size_t)n * HC + t];
        cnt++;
    }
    atomicAdd(&pooled[cur * HC + t], acc);
    if (t == 0) atomicAdd(&gcounts[cur], cnt);
}

__global__ __launch_bounds__(256) void finalize_kernel(const float* __restrict__ pooled,
                                                       const int* __restrict__ gcounts,
                                                       float* __restrict__ out) {
    int g = blockIdx.x, t = threadIdx.x;
    float c = (float)(gcounts[g] > 1 ? gcounts[g] : 1);
    out[g * HC + t] = tanhf(pooled[g * HC + t] / c);
}

// ---------------------------------------------------------------- launch
extern "C" void kernel_launch(void* const* d_in, const int* in_sizes, int n_in,
                              void* d_out, int out_size, void* d_ws, size_t ws_size,
                              hipStream_t stream) {
    const float* x         = (const float*)d_in[0];
    const int*   ei        = (const int*)d_in[1];
    const float* edge_attr = (const float*)d_in[2];
    const int*   batch     = (const int*)d_in[3];
    const float* Wl[3]  = {(const float*)d_in[4],  (const float*)d_in[10], (const float*)d_in[16]};
    const float* Wel[3] = {(const float*)d_in[5],  (const float*)d_in[11], (const float*)d_in[17]};
    const float* asl[3] = {(const float*)d_in[6],  (const float*)d_in[12], (const float*)d_in[18]};
    const float* adl[3] = {(const float*)d_in[7],  (const float*)d_in[13], (const float*)d_in[19]};
    const float* ael[3] = {(const float*)d_in[8],  (const float*)d_in[14], (const float*)d_in[20]};
    const float* bl[3]  = {(const float*)d_in[9],  (const float*)d_in[15], (const float*)d_in[21]};
    float* out = (float*)d_out;

    // workspace carve (256B aligned)
    char* p = (char*)d_ws;
    auto alloc = [&](size_t bytes) -> void* {
        void* r = (void*)p;
        p += (bytes + 255) & ~(size_t)255;
        return r;
    };
    float* hA        = (float*)alloc((size_t)N_NODES * HC * 4);
    float* hB        = (float*)alloc((size_t)N_NODES * HC * 4);
    float* a_src     = (float*)alloc((size_t)N_NODES * 4 * 4);
    float* a_dst     = (float*)alloc((size_t)N_NODES * 4 * 4);
    float4* alpha_rw = (float4*)alloc((size_t)N_EDGES * 16);
    int* counts      = (int*)alloc((size_t)N_NODES * 4);
    int* row_start   = (int*)alloc((size_t)N_NODES * 4);
    int* cursor      = (int*)alloc((size_t)N_NODES * 4);
    int* eid         = (int*)alloc((size_t)N_EDGES * 4);
    float* w_eff     = (float*)alloc(64 * 4);
    float* pooled    = (float*)alloc((size_t)N_GRAPHS * HC * 4);
    int* gcounts     = (int*)alloc((size_t)N_GRAPHS * 4);

    // zero scratch that accumulates
    zero_kernel<<<(N_NODES + 255) / 256, 256, 0, stream>>>((unsigned int*)counts, N_NODES);
    zero_kernel<<<(N_GRAPHS * HC + 255) / 256, 256, 0, stream>>>((unsigned int*)pooled, N_GRAPHS * HC);
    zero_kernel<<<1, 256, 0, stream>>>((unsigned int*)gcounts, N_GRAPHS);

    // CSR build over dst
    count_kernel<<<N_EDGES / 256, 256, 0, stream>>>(ei, counts);
    scan_kernel<<<1, 256, 0, stream>>>(counts, row_start, cursor, N_NODES);
    fill_kernel<<<N_EDGES / 256, 256, 0, stream>>>(ei, cursor, eid);

    const float* cur_in = x;
    int K = OBS;
    for (int l = 0; l < 3; ++l) {
        dim3 ggrid((N_NODES + BM - 1) / BM, HC / BN);
        gemm_kernel<<<ggrid, 256, 0, stream>>>(cur_in, Wl[l], hA, N_NODES, K);
        attdot_kernel<<<(N_NODES + 3) / 4, 256, 0, stream>>>(hA, asl[l], adl[l], a_src, a_dst);
        weff_kernel<<<1, 64, 0, stream>>>(Wel[l], ael[l], w_eff);
        alpha_kernel<<<N_EDGES / 256, 256, 0, stream>>>(ei, edge_attr, w_eff, a_src, a_dst, alpha_rw);
        aggregate_kernel<<<(N_NODES + 3) / 4, 256, 0, stream>>>(ei, eid, row_start, counts,
                                                                alpha_rw, hA, bl[l], hB);
        cur_in = hB;
        K = HC;
    }

    // global mean pool + tanh
    pool_kernel<<<(N_NODES + NPB - 1) / NPB, 256, 0, stream>>>(hB, batch, pooled, gcounts);
    finalize_kernel<<<N_GRAPHS, 256, 0, stream>>>(pooled, gcounts, out);
}

// Round 2
// 422.434 us; speedup vs baseline: 1.2539x; 1.2539x over previous
//
#include <hip/hip_runtime.h>
#include <hip/hip_bf16.h>
#include <math.h>

#define N_NODES 20000
#define N_EDGES 320000
#define N_GRAPHS 64
#define OBS 64
#define EDGE_DIM 16
#define HEADS 4
#define HID 64
#define HC 256            // HEADS*HID
#define NEG_SLOPE 0.2f
#define EPSF 1e-16f
#define N_SCAN_BLOCKS ((N_NODES + 255) / 256)   // 79

// ---------------------------------------------------------------- utilities
__global__ __launch_bounds__(256) void zero_kernel(unsigned int* __restrict__ p, int n) {
    int i = blockIdx.x * 256 + threadIdx.x;
    if (i < n) p[i] = 0u;
}

// ---------------------------------------------------------------- CSR build
__global__ __launch_bounds__(256) void count_kernel(const int* __restrict__ ei, int* __restrict__ counts) {
    int e = blockIdx.x * 256 + threadIdx.x;
    if (e >= N_EDGES) return;
    atomicAdd(&counts[ei[N_EDGES + e]], 1);
}

// two-level parallel scan: (1) per-block local exclusive scan + block total
__global__ __launch_bounds__(256) void scan_local_kernel(const int* __restrict__ counts,
                                                         int* __restrict__ row_start,
                                                         int* __restrict__ blk_tot) {
    int b = blockIdx.x, t = threadIdx.x;
    int i = b * 256 + t;
    int v = (i < N_NODES) ? counts[i] : 0;
    int lane = t & 63, w = t >> 6;
    // inclusive wave scan
    int x = v;
    #pragma unroll
    for (int off = 1; off < 64; off <<= 1) {
        int y = __shfl_up(x, off, 64);
        if (lane >= off) x += y;
    }
    __shared__ int wsum[4];
    __shared__ int woff[4];
    if (lane == 63) wsum[w] = x;
    __syncthreads();
    if (t == 0) {
        int s = 0;
        #pragma unroll
        for (int k = 0; k < 4; ++k) { woff[k] = s; s += wsum[k]; }
        blk_tot[b] = s;
    }
    __syncthreads();
    if (i < N_NODES) row_start[i] = x - v + woff[w];   // local exclusive
}

// (2) scan the 79 block totals (single tiny block)
__global__ __launch_bounds__(128) void scan_offsets_kernel(const int* __restrict__ blk_tot,
                                                           int* __restrict__ blk_off) {
    __shared__ int sd[128];
    int t = threadIdx.x;
    int v = (t < N_SCAN_BLOCKS) ? blk_tot[t] : 0;
    sd[t] = v;
    __syncthreads();
    #pragma unroll
    for (int off = 1; off < 128; off <<= 1) {
        int add = (t >= off) ? sd[t - off] : 0;
        __syncthreads();
        sd[t] += add;
        __syncthreads();
    }
    if (t < N_SCAN_BLOCKS) blk_off[t] = sd[t] - v;     // exclusive
}

// (3) add block offsets, produce row_start and cursor
__global__ __launch_bounds__(256) void scan_add_kernel(int* __restrict__ row_start,
                                                       const int* __restrict__ blk_off,
                                                       int* __restrict__ cursor) {
    int b = blockIdx.x, t = threadIdx.x;
    int i = b * 256 + t;
    if (i >= N_NODES) return;
    int r = row_start[i] + blk_off[b];
    row_start[i] = r;
    cursor[i] = r;
}

__global__ __launch_bounds__(256) void fill_kernel(const int* __restrict__ ei,
                                                   int* __restrict__ cursor,
                                                   int* __restrict__ eid) {
    int e = blockIdx.x * 256 + threadIdx.x;
    if (e >= N_EDGES) return;
    int d = ei[N_EDGES + e];
    int pos = atomicAdd(&cursor[d], 1);
    eid[pos] = e;
}

// ---------------------------------------------------------------- w_eff[h][d] = sum_c We[d, h*64+c] * att_edge[h,c]
__global__ void weff_kernel(const float* __restrict__ We, const float* __restrict__ att_edge,
                            float* __restrict__ w_eff) {
    int t = threadIdx.x;          // 64 threads
    int hh = t >> 4, d = t & 15;
    float acc = 0.f;
    #pragma unroll 8
    for (int c = 0; c < HID; ++c)
        acc += We[d * HC + hh * HID + c] * att_edge[hh * HID + c];
    w_eff[hh * 16 + d] = acc;
}

// ---------------------------------------------------------------- GEMM: C[M,256] = X[M,K] @ W[K,256]
// fused epilogue: a_src[m,head] / a_dst[m,head] (BN == HID so each block = one head)
#define BM 64
#define BN 64
#define BK 16
__global__ __launch_bounds__(256) void gemm_kernel(const float* __restrict__ X,
                                                   const float* __restrict__ W,
                                                   float* __restrict__ C, int M, int K,
                                                   const float* __restrict__ att_src,
                                                   const float* __restrict__ att_dst,
                                                   float* __restrict__ a_src,
                                                   float* __restrict__ a_dst) {
    __shared__ float As[BK][68];   // padded
    __shared__ float Bs[BK][64];
    int t = threadIdx.x;
    int tx = t & 15, ty = t >> 4;
    int m0 = blockIdx.x * BM;
    int n0 = blockIdx.y * BN;
    float acc[4][4] = {};
    for (int k0 = 0; k0 < K; k0 += BK) {
        {
            int r = t >> 2, q = t & 3;
            int m = m0 + r;
            float4 v = make_float4(0.f, 0.f, 0.f, 0.f);
            if (m < M) v = *(const float4*)(X + (size_t)m * K + k0 + q * 4);
            As[q * 4 + 0][r] = v.x;
            As[q * 4 + 1][r] = v.y;
            As[q * 4 + 2][r] = v.z;
            As[q * 4 + 3][r] = v.w;
        }
        {
            int kr = t >> 4, n4 = (t & 15) * 4;
            float4 v = *(const float4*)(W + (size_t)(k0 + kr) * HC + n0 + n4);
            *(float4*)&Bs[kr][n4] = v;
        }
        __syncthreads();
        #pragma unroll
        for (int kk = 0; kk < BK; ++kk) {
            float4 a4 = *(const float4*)&As[kk][ty * 4];
            float4 b4 = *(const float4*)&Bs[kk][tx * 4];
            float av[4] = {a4.x, a4.y, a4.z, a4.w};
            float bv[4] = {b4.x, b4.y, b4.z, b4.w};
            #pragma unroll
            for (int i = 0; i < 4; ++i)
                #pragma unroll
                for (int j = 0; j < 4; ++j)
                    acc[i][j] += av[i] * bv[j];
        }
        __syncthreads();
    }
    #pragma unroll
    for (int i = 0; i < 4; ++i) {
        int m = m0 + ty * 4 + i;
        if (m < M)
            *(float4*)(C + (size_t)m * HC + n0 + tx * 4) =
                make_float4(acc[i][0], acc[i][1], acc[i][2], acc[i][3]);
    }
    // ---- fused attdot epilogue: this block covers head = n0/64
    {
        int head = n0 >> 6;
        float as[4], ad[4];
        #pragma unroll
        for (int j = 0; j < 4; ++j) {
            as[j] = att_src[head * HID + tx * 4 + j];
            ad[j] = att_dst[head * HID + tx * 4 + j];
        }
        #pragma unroll
        for (int i = 0; i < 4; ++i) {
            float ps = 0.f, pd = 0.f;
            #pragma unroll
            for (int j = 0; j < 4; ++j) {
                ps += acc[i][j] * as[j];
                pd += acc[i][j] * ad[j];
            }
            #pragma unroll
            for (int o = 8; o > 0; o >>= 1) {   // reduce across 16-lane tx group
                ps += __shfl_xor(ps, o, 64);
                pd += __shfl_xor(pd, o, 64);
            }
            int m = m0 + ty * 4 + i;
            if (tx == 0 && m < M) {
                a_src[(size_t)m * 4 + head] = ps;
                a_dst[(size_t)m * 4 + head] = pd;
            }
        }
    }
}

// ---------------------------------------------------------------- per-edge raw attention logits
__global__ __launch_bounds__(256) void alpha_kernel(const int* __restrict__ ei,
                                                    const float* __restrict__ edge_attr,
                                                    const float* __restrict__ w_eff,
                                                    const float* __restrict__ a_src,
                                                    const float* __restrict__ a_dst,
                                                    float4* __restrict__ alpha_out) {
    __shared__ float wsh[64];
    int t = threadIdx.x;
    if (t < 64) wsh[t] = w_eff[t];
    __syncthreads();
    int e = blockIdx.x * 256 + t;
    if (e >= N_EDGES) return;
    int s = ei[e], d = ei[N_EDGES + e];
    const float* ea = edge_attr + (size_t)e * EDGE_DIM;
    float x[16];
    #pragma unroll
    for (int i = 0; i < 16; i += 4) {
        float4 v = *(const float4*)(ea + i);
        x[i] = v.x; x[i + 1] = v.y; x[i + 2] = v.z; x[i + 3] = v.w;
    }
    float4 as = *(const float4*)(a_src + (size_t)s * 4);
    float4 ad = *(const float4*)(a_dst + (size_t)d * 4);
    float asv[4] = {as.x, as.y, as.z, as.w};
    float adv[4] = {ad.x, ad.y, ad.z, ad.w};
    float al[4];
    #pragma unroll
    for (int hh = 0; hh < 4; ++hh) {
        float acc = 0.f;
        #pragma unroll
        for (int i = 0; i < 16; ++i) acc += x[i] * wsh[hh * 16 + i];
        float v = asv[hh] + adv[hh] + acc;
        al[hh] = v > 0.f ? v : NEG_SLOPE * v;   // leaky_relu
    }
    alpha_out[e] = make_float4(al[0], al[1], al[2], al[3]);
}

// ---------------------------------------------------------------- aggregate: wave per node, online softmax + gather
__global__ __launch_bounds__(256) void aggregate_kernel(const int* __restrict__ ei,
                                                        const int* __restrict__ eid,
                                                        const int* __restrict__ row_start,
                                                        const int* __restrict__ counts,
                                                        const float4* __restrict__ alpha_raw,
                                                        const float* __restrict__ h,
                                                        const float* __restrict__ bias,
                                                        float* __restrict__ out) {
    int wid = threadIdx.x >> 6, lane = threadIdx.x & 63;
    int n = blockIdx.x * 4 + wid;
    if (n >= N_NODES) return;
    int start = row_start[n];
    int deg = counts[n];

    float m0 = -INFINITY, m1 = -INFINITY, m2 = -INFINITY, m3 = -INFINITY;
    for (int i = lane; i < deg; i += 64) {
        float4 a = alpha_raw[eid[start + i]];
        m0 = fmaxf(m0, a.x); m1 = fmaxf(m1, a.y);
        m2 = fmaxf(m2, a.z); m3 = fmaxf(m3, a.w);
    }
    #pragma unroll
    for (int o = 32; o > 0; o >>= 1) {
        m0 = fmaxf(m0, __shfl_xor(m0, o, 64));
        m1 = fmaxf(m1, __shfl_xor(m1, o, 64));
        m2 = fmaxf(m2, __shfl_xor(m2, o, 64));
        m3 = fmaxf(m3, __shfl_xor(m3, o, 64));
    }

    float acc0 = 0.f, acc1 = 0.f, acc2 = 0.f, acc3 = 0.f;
    float d0 = 0.f, d1 = 0.f, d2 = 0.f, d3 = 0.f;
    const int* ep = eid + start;
    for (int i = 0; i < deg; ++i) {
        int e = ep[i];
        int s = ei[e];
        float4 a = alpha_raw[e];
        float e0 = __expf(a.x - m0);
        float e1 = __expf(a.y - m1);
        float e2 = __expf(a.z - m2);
        float e3 = __expf(a.w - m3);
        d0 += e0; d1 += e1; d2 += e2; d3 += e3;
        const float* hr = h + (size_t)s * HC;
        acc0 += e0 * hr[lane];
        acc1 += e1 * hr[64 + lane];
        acc2 += e2 * hr[128 + lane];
        acc3 += e3 * hr[192 + lane];
    }
    float r0 = acc0 / (d0 + EPSF) + bias[lane];
    float r1 = acc1 / (d1 + EPSF) + bias[64 + lane];
    float r2 = acc2 / (d2 + EPSF) + bias[128 + lane];
    float r3 = acc3 / (d3 + EPSF) + bias[192 + lane];
    float* o = out + (size_t)n * HC;
    o[lane]       = fmaxf(r0, 0.f);
    o[64 + lane]  = fmaxf(r1, 0.f);
    o[128 + lane] = fmaxf(r2, 0.f);
    o[192 + lane] = fmaxf(r3, 0.f);
}

// ---------------------------------------------------------------- pooling (batch is sorted)
#define NPB 100
__global__ __launch_bounds__(256) void pool_kernel(const float* __restrict__ h,
                                                   const int* __restrict__ batch,
                                                   float* __restrict__ pooled,
                                                   int* __restrict__ gcounts) {
    int t = threadIdx.x;
    int n0 = blockIdx.x * NPB;
    int n1 = n0 + NPB;
    if (n1 > N_NODES) n1 = N_NODES;
    if (n0 >= N_NODES) return;
    int cur = batch[n0];
    float acc = 0.f;
    int cnt = 0;
    for (int n = n0; n < n1; ++n) {
        int g = batch[n];
        if (g != cur) {
            atomicAdd(&pooled[cur * HC + t], acc);
            if (t == 0) atomicAdd(&gcounts[cur], cnt);
            acc = 0.f; cnt = 0; cur = g;
        }
        acc += h[(size_t)n * HC + t];
        cnt++;
    }
    atomicAdd(&pooled[cur * HC + t], acc);
    if (t == 0) atomicAdd(&gcounts[cur], cnt);
}

__global__ __launch_bounds__(256) void finalize_kernel(const float* __restrict__ pooled,
                                                       const int* __restrict__ gcounts,
                                                       float* __restrict__ out) {
    int g = blockIdx.x, t = threadIdx.x;
    float c = (float)(gcounts[g] > 1 ? gcounts[g] : 1);
    out[g * HC + t] = tanhf(pooled[g * HC + t] / c);
}

// ---------------------------------------------------------------- launch
extern "C" void kernel_launch(void* const* d_in, const int* in_sizes, int n_in,
                              void* d_out, int out_size, void* d_ws, size_t ws_size,
                              hipStream_t stream) {
    const float* x         = (const float*)d_in[0];
    const int*   ei        = (const int*)d_in[1];
    const float* edge_attr = (const float*)d_in[2];
    const int*   batch     = (const int*)d_in[3];
    const float* Wl[3]  = {(const float*)d_in[4],  (const float*)d_in[10], (const float*)d_in[16]};
    const float* Wel[3] = {(const float*)d_in[5],  (const float*)d_in[11], (const float*)d_in[17]};
    const float* asl[3] = {(const float*)d_in[6],  (const float*)d_in[12], (const float*)d_in[18]};
    const float* adl[3] = {(const float*)d_in[7],  (const float*)d_in[13], (const float*)d_in[19]};
    const float* ael[3] = {(const float*)d_in[8],  (const float*)d_in[14], (const float*)d_in[20]};
    const float* bl[3]  = {(const float*)d_in[9],  (const float*)d_in[15], (const float*)d_in[21]};
    float* out = (float*)d_out;

    // workspace carve (256B aligned)
    char* p = (char*)d_ws;
    auto alloc = [&](size_t bytes) -> void* {
        void* r = (void*)p;
        p += (bytes + 255) & ~(size_t)255;
        return r;
    };
    float* hA        = (float*)alloc((size_t)N_NODES * HC * 4);
    float* hB        = (float*)alloc((size_t)N_NODES * HC * 4);
    float* a_src     = (float*)alloc((size_t)N_NODES * 4 * 4);
    float* a_dst     = (float*)alloc((size_t)N_NODES * 4 * 4);
    float4* alpha_rw = (float4*)alloc((size_t)N_EDGES * 16);
    int* counts      = (int*)alloc((size_t)N_NODES * 4);
    int* row_start   = (int*)alloc((size_t)N_NODES * 4);
    int* cursor      = (int*)alloc((size_t)N_NODES * 4);
    int* eid         = (int*)alloc((size_t)N_EDGES * 4);
    float* w_eff     = (float*)alloc(64 * 4);
    float* pooled    = (float*)alloc((size_t)N_GRAPHS * HC * 4);
    int* gcounts     = (int*)alloc((size_t)N_GRAPHS * 4);
    int* blk_tot     = (int*)alloc((size_t)N_SCAN_BLOCKS * 4);
    int* blk_off     = (int*)alloc((size_t)N_SCAN_BLOCKS * 4);

    // zero scratch that accumulates
    zero_kernel<<<(N_NODES + 255) / 256, 256, 0, stream>>>((unsigned int*)counts, N_NODES);
    zero_kernel<<<(N_GRAPHS * HC + 255) / 256, 256, 0, stream>>>((unsigned int*)pooled, N_GRAPHS * HC);
    zero_kernel<<<1, 256, 0, stream>>>((unsigned int*)gcounts, N_GRAPHS);

    // CSR build over dst (parallel two-level scan)
    count_kernel<<<N_EDGES / 256, 256, 0, stream>>>(ei, counts);
    scan_local_kernel<<<N_SCAN_BLOCKS, 256, 0, stream>>>(counts, row_start, blk_tot);
    scan_offsets_kernel<<<1, 128, 0, stream>>>(blk_tot, blk_off);
    scan_add_kernel<<<N_SCAN_BLOCKS, 256, 0, stream>>>(row_start, blk_off, cursor);
    fill_kernel<<<N_EDGES / 256, 256, 0, stream>>>(ei, cursor, eid);

    const float* cur_in = x;
    int K = OBS;
    for (int l = 0; l < 3; ++l) {
        dim3 ggrid((N_NODES + BM - 1) / BM, HC / BN);
        gemm_kernel<<<ggrid, 256, 0, stream>>>(cur_in, Wl[l], hA, N_NODES, K,
                                               asl[l], adl[l], a_src, a_dst);
        weff_kernel<<<1, 64, 0, stream>>>(Wel[l], ael[l], w_eff);
        alpha_kernel<<<N_EDGES / 256, 256, 0, stream>>>(ei, edge_attr, w_eff, a_src, a_dst, alpha_rw);
        aggregate_kernel<<<(N_NODES + 3) / 4, 256, 0, stream>>>(ei, eid, row_start, counts,
                                                                alpha_rw, hA, bl[l], hB);
        cur_in = hB;
        K = HC;
    }

    // global mean pool + tanh
    pool_kernel<<<(N_NODES + NPB - 1) / NPB, 256, 0, stream>>>(hB, batch, pooled, gcounts);
    finalize_kernel<<<N_GRAPHS, 256, 0, stream>>>(pooled, gcounts, out);
}

// Round 3
// 310.017 us; speedup vs baseline: 1.7086x; 1.3626x over previous
//
#include <hip/hip_runtime.h>
#include <hip/hip_bf16.h>
#include <hip/hip_fp16.h>
#include <math.h>

#define N_NODES 20000
#define N_EDGES 320000
#define N_GRAPHS 64
#define OBS 64
#define EDGE_DIM 16
#define HEADS 4
#define HID 64
#define HC 256            // HEADS*HID
#define NEG_SLOPE 0.2f
#define EPSF 1e-16f
#define N_SCAN_BLOCKS ((N_NODES + 255) / 256)   // 79

// ---------------------------------------------------------------- utilities
__global__ __launch_bounds__(256) void zero_kernel(unsigned int* __restrict__ p, int n) {
    int i = blockIdx.x * 256 + threadIdx.x;
    if (i < n) p[i] = 0u;
}

// ---------------------------------------------------------------- CSR build
__global__ __launch_bounds__(256) void count_kernel(const int* __restrict__ ei, int* __restrict__ counts) {
    int e = blockIdx.x * 256 + threadIdx.x;
    if (e >= N_EDGES) return;
    atomicAdd(&counts[ei[N_EDGES + e]], 1);
}

__global__ __launch_bounds__(256) void scan_local_kernel(const int* __restrict__ counts,
                                                         int* __restrict__ row_start,
                                                         int* __restrict__ blk_tot) {
    int b = blockIdx.x, t = threadIdx.x;
    int i = b * 256 + t;
    int v = (i < N_NODES) ? counts[i] : 0;
    int lane = t & 63, w = t >> 6;
    int x = v;
    #pragma unroll
    for (int off = 1; off < 64; off <<= 1) {
        int y = __shfl_up(x, off, 64);
        if (lane >= off) x += y;
    }
    __shared__ int wsum[4];
    __shared__ int woff[4];
    if (lane == 63) wsum[w] = x;
    __syncthreads();
    if (t == 0) {
        int s = 0;
        #pragma unroll
        for (int k = 0; k < 4; ++k) { woff[k] = s; s += wsum[k]; }
        blk_tot[b] = s;
    }
    __syncthreads();
    if (i < N_NODES) row_start[i] = x - v + woff[w];
}

__global__ __launch_bounds__(128) void scan_offsets_kernel(const int* __restrict__ blk_tot,
                                                           int* __restrict__ blk_off) {
    __shared__ int sd[128];
    int t = threadIdx.x;
    int v = (t < N_SCAN_BLOCKS) ? blk_tot[t] : 0;
    sd[t] = v;
    __syncthreads();
    #pragma unroll
    for (int off = 1; off < 128; off <<= 1) {
        int add = (t >= off) ? sd[t - off] : 0;
        __syncthreads();
        sd[t] += add;
        __syncthreads();
    }
    if (t < N_SCAN_BLOCKS) blk_off[t] = sd[t] - v;
}

__global__ __launch_bounds__(256) void scan_add_kernel(int* __restrict__ row_start,
                                                       const int* __restrict__ blk_off,
                                                       int* __restrict__ cursor) {
    int b = blockIdx.x, t = threadIdx.x;
    int i = b * 256 + t;
    if (i >= N_NODES) return;
    int r = row_start[i] + blk_off[b];
    row_start[i] = r;
    cursor[i] = r;
}

// fill: also materialize src in CSR order + edge->pos map
__global__ __launch_bounds__(256) void fill_kernel(const int* __restrict__ ei,
                                                   int* __restrict__ cursor,
                                                   int* __restrict__ src_csr,
                                                   int* __restrict__ edge_pos) {
    int e = blockIdx.x * 256 + threadIdx.x;
    if (e >= N_EDGES) return;
    int s = ei[e];
    int d = ei[N_EDGES + e];
    int pos = atomicAdd(&cursor[d], 1);
    src_csr[pos] = s;
    edge_pos[e] = pos;
}

// ---------------------------------------------------------------- w_eff[h][d] = sum_c We[d, h*64+c] * att_edge[h,c]
__global__ void weff_kernel(const float* __restrict__ We, const float* __restrict__ att_edge,
                            float* __restrict__ w_eff) {
    int t = threadIdx.x;          // 64 threads
    int hh = t >> 4, d = t & 15;
    float acc = 0.f;
    #pragma unroll 8
    for (int c = 0; c < HID; ++c)
        acc += We[d * HC + hh * HID + c] * att_edge[hh * HID + c];
    w_eff[hh * 16 + d] = acc;
}

// ---------------------------------------------------------------- GEMM: C16[M,256] = fp16(X[M,K] @ W[K,256])
// fused epilogue: a_src[m,head] / a_dst[m,head] (BN == HID so each block = one head)
#define BM 64
#define BN 64
#define BK 16
__global__ __launch_bounds__(256) void gemm_kernel(const float* __restrict__ X,
                                                   const float* __restrict__ W,
                                                   __half* __restrict__ C16, int M, int K,
                                                   const float* __restrict__ att_src,
                                                   const float* __restrict__ att_dst,
                                                   float* __restrict__ a_src,
                                                   float* __restrict__ a_dst) {
    __shared__ float As[BK][68];   // padded
    __shared__ float Bs[BK][64];
    int t = threadIdx.x;
    int tx = t & 15, ty = t >> 4;
    int m0 = blockIdx.x * BM;
    int n0 = blockIdx.y * BN;
    float acc[4][4] = {};
    for (int k0 = 0; k0 < K; k0 += BK) {
        {
            int r = t >> 2, q = t & 3;
            int m = m0 + r;
            float4 v = make_float4(0.f, 0.f, 0.f, 0.f);
            if (m < M) v = *(const float4*)(X + (size_t)m * K + k0 + q * 4);
            As[q * 4 + 0][r] = v.x;
            As[q * 4 + 1][r] = v.y;
            As[q * 4 + 2][r] = v.z;
            As[q * 4 + 3][r] = v.w;
        }
        {
            int kr = t >> 4, n4 = (t & 15) * 4;
            float4 v = *(const float4*)(W + (size_t)(k0 + kr) * HC + n0 + n4);
            *(float4*)&Bs[kr][n4] = v;
        }
        __syncthreads();
        #pragma unroll
        for (int kk = 0; kk < BK; ++kk) {
            float4 a4 = *(const float4*)&As[kk][ty * 4];
            float4 b4 = *(const float4*)&Bs[kk][tx * 4];
            float av[4] = {a4.x, a4.y, a4.z, a4.w};
            float bv[4] = {b4.x, b4.y, b4.z, b4.w};
            #pragma unroll
            for (int i = 0; i < 4; ++i)
                #pragma unroll
                for (int j = 0; j < 4; ++j)
                    acc[i][j] += av[i] * bv[j];
        }
        __syncthreads();
    }
    #pragma unroll
    for (int i = 0; i < 4; ++i) {
        int m = m0 + ty * 4 + i;
        if (m < M) {
            __half2 p0 = __floats2half2_rn(acc[i][0], acc[i][1]);
            __half2 p1 = __floats2half2_rn(acc[i][2], acc[i][3]);
            __half* dst = C16 + (size_t)m * HC + n0 + tx * 4;
            *(__half2*)dst       = p0;
            *(__half2*)(dst + 2) = p1;
        }
    }
    // ---- fused attdot epilogue: this block covers head = n0/64
    {
        int head = n0 >> 6;
        float as[4], ad[4];
        #pragma unroll
        for (int j = 0; j < 4; ++j) {
            as[j] = att_src[head * HID + tx * 4 + j];
            ad[j] = att_dst[head * HID + tx * 4 + j];
        }
        #pragma unroll
        for (int i = 0; i < 4; ++i) {
            float ps = 0.f, pd = 0.f;
            #pragma unroll
            for (int j = 0; j < 4; ++j) {
                ps += acc[i][j] * as[j];
                pd += acc[i][j] * ad[j];
            }
            #pragma unroll
            for (int o = 8; o > 0; o >>= 1) {
                ps += __shfl_xor(ps, o, 64);
                pd += __shfl_xor(pd, o, 64);
            }
            int m = m0 + ty * 4 + i;
            if (tx == 0 && m < M) {
                a_src[(size_t)m * 4 + head] = ps;
                a_dst[(size_t)m * 4 + head] = pd;
            }
        }
    }
}

// ---------------------------------------------------------------- per-edge raw attention logits -> CSR order
__global__ __launch_bounds__(256) void alpha_kernel(const int* __restrict__ ei,
                                                    const float* __restrict__ edge_attr,
                                                    const float* __restrict__ w_eff,
                                                    const float* __restrict__ a_src,
                                                    const float* __restrict__ a_dst,
                                                    const int* __restrict__ edge_pos,
                                                    float4* __restrict__ alpha_csr) {
    __shared__ float wsh[64];
    int t = threadIdx.x;
    if (t < 64) wsh[t] = w_eff[t];
    __syncthreads();
    int e = blockIdx.x * 256 + t;
    if (e >= N_EDGES) return;
    int s = ei[e], d = ei[N_EDGES + e];
    const float* ea = edge_attr + (size_t)e * EDGE_DIM;
    float x[16];
    #pragma unroll
    for (int i = 0; i < 16; i += 4) {
        float4 v = *(const float4*)(ea + i);
        x[i] = v.x; x[i + 1] = v.y; x[i + 2] = v.z; x[i + 3] = v.w;
    }
    float4 as = *(const float4*)(a_src + (size_t)s * 4);
    float4 ad = *(const float4*)(a_dst + (size_t)d * 4);
    float asv[4] = {as.x, as.y, as.z, as.w};
    float adv[4] = {ad.x, ad.y, ad.z, ad.w};
    float al[4];
    #pragma unroll
    for (int hh = 0; hh < 4; ++hh) {
        float acc = 0.f;
        #pragma unroll
        for (int i = 0; i < 16; ++i) acc += x[i] * wsh[hh * 16 + i];
        float v = asv[hh] + adv[hh] + acc;
        al[hh] = v > 0.f ? v : NEG_SLOPE * v;   // leaky_relu
    }
    alpha_csr[edge_pos[e]] = make_float4(al[0], al[1], al[2], al[3]);
}

// ---------------------------------------------------------------- aggregate: wave per node, softmax + fp16 gather
// lane l handles channels (2l,2l+1) [heads 0/1] and (128+2l,128+2l+1) [heads 2/3]
__global__ __launch_bounds__(256) void aggregate_kernel(const int* __restrict__ src_csr,
                                                        const float4* __restrict__ alpha_csr,
                                                        const int* __restrict__ row_start,
                                                        const int* __restrict__ counts,
                                                        const __half* __restrict__ h16,
                                                        const float* __restrict__ bias,
                                                        float* __restrict__ out) {
    int wid = threadIdx.x >> 6, lane = threadIdx.x & 63;
    int n = blockIdx.x * 4 + wid;
    if (n >= N_NODES) return;
    int start = row_start[n];
    int deg = counts[n];
    const float4* ap = alpha_csr + start;
    const int* sp = src_csr + start;

    // pass A: per-head max over incoming edges (lane-parallel, sequential reads)
    float m0 = -INFINITY, m1 = -INFINITY, m2 = -INFINITY, m3 = -INFINITY;
    for (int i = lane; i < deg; i += 64) {
        float4 a = ap[i];
        m0 = fmaxf(m0, a.x); m1 = fmaxf(m1, a.y);
        m2 = fmaxf(m2, a.z); m3 = fmaxf(m3, a.w);
    }
    #pragma unroll
    for (int o = 32; o > 0; o >>= 1) {
        m0 = fmaxf(m0, __shfl_xor(m0, o, 64));
        m1 = fmaxf(m1, __shfl_xor(m1, o, 64));
        m2 = fmaxf(m2, __shfl_xor(m2, o, 64));
        m3 = fmaxf(m3, __shfl_xor(m3, o, 64));
    }
    bool lo = (lane < 32);
    float mA = lo ? m0 : m1;          // head for channels 2l
    float mB = lo ? m2 : m3;          // head for channels 128+2l

    // pass B: serial over edges; prefetch src one iteration ahead
    float aAx = 0.f, aAy = 0.f, aBx = 0.f, aBy = 0.f;
    float dA = 0.f, dB = 0.f;
    int s_next = (deg > 0) ? sp[0] : 0;
    #pragma unroll 2
    for (int i = 0; i < deg; ++i) {
        int s = s_next;
        if (i + 1 < deg) s_next = sp[i + 1];
        float4 a = ap[i];
        float eA = __expf((lo ? a.x : a.y) - mA);
        float eB = __expf((lo ? a.z : a.w) - mB);
        dA += eA; dB += eB;
        const __half2* hr = (const __half2*)(h16 + (size_t)s * HC);
        __half2 vA = hr[lane];        // channels 2l, 2l+1
        __half2 vB = hr[64 + lane];   // channels 128+2l, 128+2l+1
        float2 fA = __half22float2(vA);
        float2 fB = __half22float2(vB);
        aAx += eA * fA.x; aAy += eA * fA.y;
        aBx += eB * fB.x; aBy += eB * fB.y;
    }
    float2 b01 = *(const float2*)(bias + 2 * lane);
    float2 b23 = *(const float2*)(bias + 128 + 2 * lane);
    float invA = 1.f / (dA + EPSF);
    float invB = 1.f / (dB + EPSF);
    float2 r01 = make_float2(fmaxf(aAx * invA + b01.x, 0.f), fmaxf(aAy * invA + b01.y, 0.f));
    float2 r23 = make_float2(fmaxf(aBx * invB + b23.x, 0.f), fmaxf(aBy * invB + b23.y, 0.f));
    float* o = out + (size_t)n * HC;
    *(float2*)(o + 2 * lane)       = r01;
    *(float2*)(o + 128 + 2 * lane) = r23;
}

// ---------------------------------------------------------------- pooling (batch is sorted)
#define NPB 100
__global__ __launch_bounds__(256) void pool_kernel(const float* __restrict__ h,
                                                   const int* __restrict__ batch,
                                                   float* __restrict__ pooled,
                                                   int* __restrict__ gcounts) {
    int t = threadIdx.x;
    int n0 = blockIdx.x * NPB;
    int n1 = n0 + NPB;
    if (n1 > N_NODES) n1 = N_NODES;
    if (n0 >= N_NODES) return;
    int cur = batch[n0];
    float acc = 0.f;
    int cnt = 0;
    for (int n = n0; n < n1; ++n) {
        int g = batch[n];
        if (g != cur) {
            atomicAdd(&pooled[cur * HC + t], acc);
            if (t == 0) atomicAdd(&gcounts[cur], cnt);
            acc = 0.f; cnt = 0; cur = g;
        }
        acc += h[(size_t)n * HC + t];
        cnt++;
    }
    atomicAdd(&pooled[cur * HC + t], acc);
    if (t == 0) atomicAdd(&gcounts[cur], cnt);
}

__global__ __launch_bounds__(256) void finalize_kernel(const float* __restrict__ pooled,
                                                       const int* __restrict__ gcounts,
                                                       float* __restrict__ out) {
    int g = blockIdx.x, t = threadIdx.x;
    float c = (float)(gcounts[g] > 1 ? gcounts[g] : 1);
    out[g * HC + t] = tanhf(pooled[g * HC + t] / c);
}

// ---------------------------------------------------------------- launch
extern "C" void kernel_launch(void* const* d_in, const int* in_sizes, int n_in,
                              void* d_out, int out_size, void* d_ws, size_t ws_size,
                              hipStream_t stream) {
    const float* x         = (const float*)d_in[0];
    const int*   ei        = (const int*)d_in[1];
    const float* edge_attr = (const float*)d_in[2];
    const int*   batch     = (const int*)d_in[3];
    const float* Wl[3]  = {(const float*)d_in[4],  (const float*)d_in[10], (const float*)d_in[16]};
    const float* Wel[3] = {(const float*)d_in[5],  (const float*)d_in[11], (const float*)d_in[17]};
    const float* asl[3] = {(const float*)d_in[6],  (const float*)d_in[12], (const float*)d_in[18]};
    const float* adl[3] = {(const float*)d_in[7],  (const float*)d_in[13], (const float*)d_in[19]};
    const float* ael[3] = {(const float*)d_in[8],  (const float*)d_in[14], (const float*)d_in[20]};
    const float* bl[3]  = {(const float*)d_in[9],  (const float*)d_in[15], (const float*)d_in[21]};
    float* out = (float*)d_out;

    // workspace carve (256B aligned)
    char* p = (char*)d_ws;
    auto alloc = [&](size_t bytes) -> void* {
        void* r = (void*)p;
        p += (bytes + 255) & ~(size_t)255;
        return r;
    };
    __half* h16       = (__half*)alloc((size_t)N_NODES * HC * 2);
    float* hB         = (float*)alloc((size_t)N_NODES * HC * 4);
    float* a_src      = (float*)alloc((size_t)N_NODES * 4 * 4);
    float* a_dst      = (float*)alloc((size_t)N_NODES * 4 * 4);
    float4* alpha_csr = (float4*)alloc((size_t)N_EDGES * 16);
    int* counts       = (int*)alloc((size_t)N_NODES * 4);
    int* row_start    = (int*)alloc((size_t)N_NODES * 4);
    int* cursor       = (int*)alloc((size_t)N_NODES * 4);
    int* src_csr      = (int*)alloc((size_t)N_EDGES * 4);
    int* edge_pos     = (int*)alloc((size_t)N_EDGES * 4);
    float* w_eff      = (float*)alloc(64 * 4);
    float* pooled     = (float*)alloc((size_t)N_GRAPHS * HC * 4);
    int* gcounts      = (int*)alloc((size_t)N_GRAPHS * 4);
    int* blk_tot      = (int*)alloc((size_t)N_SCAN_BLOCKS * 4);
    int* blk_off      = (int*)alloc((size_t)N_SCAN_BLOCKS * 4);

    // zero scratch that accumulates
    zero_kernel<<<(N_NODES + 255) / 256, 256, 0, stream>>>((unsigned int*)counts, N_NODES);
    zero_kernel<<<(N_GRAPHS * HC + 255) / 256, 256, 0, stream>>>((unsigned int*)pooled, N_GRAPHS * HC);
    zero_kernel<<<1, 256, 0, stream>>>((unsigned int*)gcounts, N_GRAPHS);

    // CSR build over dst (parallel two-level scan)
    count_kernel<<<N_EDGES / 256, 256, 0, stream>>>(ei, counts);
    scan_local_kernel<<<N_SCAN_BLOCKS, 256, 0, stream>>>(counts, row_start, blk_tot);
    scan_offsets_kernel<<<1, 128, 0, stream>>>(blk_tot, blk_off);
    scan_add_kernel<<<N_SCAN_BLOCKS, 256, 0, stream>>>(row_start, blk_off, cursor);
    fill_kernel<<<N_EDGES / 256, 256, 0, stream>>>(ei, cursor, src_csr, edge_pos);

    const float* cur_in = x;
    int K = OBS;
    for (int l = 0; l < 3; ++l) {
        dim3 ggrid((N_NODES + BM - 1) / BM, HC / BN);
        gemm_kernel<<<ggrid, 256, 0, stream>>>(cur_in, Wl[l], h16, N_NODES, K,
                                               asl[l], adl[l], a_src, a_dst);
        weff_kernel<<<1, 64, 0, stream>>>(Wel[l], ael[l], w_eff);
        alpha_kernel<<<N_EDGES / 256, 256, 0, stream>>>(ei, edge_attr, w_eff, a_src, a_dst,
                                                        edge_pos, alpha_csr);
        aggregate_kernel<<<(N_NODES + 3) / 4, 256, 0, stream>>>(src_csr, alpha_csr, row_start,
                                                                counts, h16, bl[l], hB);
        cur_in = hB;
        K = HC;
    }

    // global mean pool + tanh
    pool_kernel<<<(N_NODES + NPB - 1) / NPB, 256, 0, stream>>>(hB, batch, pooled, gcounts);
    finalize_kernel<<<N_GRAPHS, 256, 0, stream>>>(pooled, gcounts, out);
}